// Round 3
// baseline (740.829 us; speedup 1.0000x reference)
//
#include <hip/hip_runtime.h>
#include <hip/hip_bf16.h>

#define D_IN   128
#define D_OUT  64
#define CAP    64          // per-node bucket capacity; overflow handled exactly
#define TN     32          // nodes per proj LDS tile
#define PROJ_BLOCKS   1024
#define BUCKET_BLOCKS 512

// ---------------------------------------------------------------------------
// Fused prep: blocks [0,PROJ_BLOCKS) do the projection GEMM (LDS x-tile,
// W in per-lane registers, 4-node ILP); blocks [PROJ_BLOCKS, +BUCKET_BLOCKS)
// build the per-destination edge buckets.
// ---------------------------------------------------------------------------
__global__ __launch_bounds__(256, 2)
void prep_kernel(const float* __restrict__ x, const float* __restrict__ W,
                 const float* __restrict__ bvec, float* __restrict__ h,
                 const int* __restrict__ row, const int* __restrict__ col,
                 int* __restrict__ deg, int* __restrict__ bucket,
                 int* __restrict__ ovf_cnt, int* __restrict__ ovf_list,
                 int ovf_cap, int n_nodes, int n_edges) {
    __shared__ float4 xs[TN][D_IN / 4];   // 16 KB

    if (blockIdx.x >= PROJ_BLOCKS) {
        // ---- bucket part (grid-stride over edges) ----
        const int stride = BUCKET_BLOCKS * 256;
        for (int e = (blockIdx.x - PROJ_BLOCKS) * 256 + threadIdx.x;
             e < n_edges; e += stride) {
            const int r = row[e];
            const int c = col[e];
            const int p = atomicAdd(&deg[r], 1);
            if (p < CAP) {
                bucket[(size_t)r * CAP + p] = c;
            } else {
                const int i = atomicAdd(ovf_cnt, 1);
                if (i < ovf_cap) ovf_list[i] = e;
            }
        }
        return;
    }

    // ---- projection part ----
    const int lane = threadIdx.x & 63;
    const int wid  = threadIdx.x >> 6;

    float4 w4[D_IN / 4];                  // this lane's W row: 128 VGPRs
#pragma unroll
    for (int i = 0; i < D_IN / 4; ++i)
        w4[i] = ((const float4*)W)[lane * (D_IN / 4) + i];
    const float bias = bvec[lane];

    const int ntiles = (n_nodes + TN - 1) / TN;
    for (int tile = blockIdx.x; tile < ntiles; tile += PROJ_BLOCKS) {
        const int base = tile * TN;
        // cooperative tile load: 32 rows x 32 float4 = 1024 float4, 4/thread
#pragma unroll
        for (int i = 0; i < (TN * (D_IN / 4)) / 256; ++i) {
            const int idx = threadIdx.x + i * 256;
            const int r = idx >> 5;
            const int c = idx & 31;
            const int gr = base + r;
            if (gr < n_nodes)
                xs[r][c] = ((const float4*)x)[(size_t)gr * (D_IN / 4) + c];
        }
        __syncthreads();

        // each wave: 8 nodes, 2 groups of 4 with independent acc chains
#pragma unroll
        for (int g = 0; g < 2; ++g) {
            const int n0 = wid * 8 + g * 4;
            float a0 = bias, a1 = bias, a2 = bias, a3 = bias;
#pragma unroll
            for (int kc = 0; kc < D_IN / 4; ++kc) {
                const float4 ww = w4[kc];
                const float4 f0 = xs[n0 + 0][kc];   // ds_read_b128 broadcast
                const float4 f1 = xs[n0 + 1][kc];
                const float4 f2 = xs[n0 + 2][kc];
                const float4 f3 = xs[n0 + 3][kc];
                a0 = fmaf(f0.x, ww.x, a0); a0 = fmaf(f0.y, ww.y, a0);
                a0 = fmaf(f0.z, ww.z, a0); a0 = fmaf(f0.w, ww.w, a0);
                a1 = fmaf(f1.x, ww.x, a1); a1 = fmaf(f1.y, ww.y, a1);
                a1 = fmaf(f1.z, ww.z, a1); a1 = fmaf(f1.w, ww.w, a1);
                a2 = fmaf(f2.x, ww.x, a2); a2 = fmaf(f2.y, ww.y, a2);
                a2 = fmaf(f2.z, ww.z, a2); a2 = fmaf(f2.w, ww.w, a2);
                a3 = fmaf(f3.x, ww.x, a3); a3 = fmaf(f3.y, ww.y, a3);
                a3 = fmaf(f3.z, ww.z, a3); a3 = fmaf(f3.w, ww.w, a3);
            }
            const int nn = base + n0;
            if (nn + 0 < n_nodes) h[(size_t)(nn + 0) * D_OUT + lane] = a0;
            if (nn + 1 < n_nodes) h[(size_t)(nn + 1) * D_OUT + lane] = a1;
            if (nn + 2 < n_nodes) h[(size_t)(nn + 2) * D_OUT + lane] = a2;
            if (nn + 3 < n_nodes) h[(size_t)(nn + 3) * D_OUT + lane] = a3;
        }
        __syncthreads();
    }
}

// ---------------------------------------------------------------------------
// Gather with fused mean: one wave per node; lanes hold bucket cols, shfl
// broadcast, accumulate h rows, write sum * (1/max(deg,1)).
// ---------------------------------------------------------------------------
__global__ void gather_kernel(const float* __restrict__ h,
                              const int* __restrict__ deg,
                              const int* __restrict__ bucket,
                              float* __restrict__ out,
                              int n_nodes) {
    const int lane = threadIdx.x & 63;
    int wave = (int)((blockIdx.x * blockDim.x + threadIdx.x) >> 6);
    const int nwaves = (int)((gridDim.x * blockDim.x) >> 6);

    for (int node = wave; node < n_nodes; node += nwaves) {
        const int d = deg[node];                 // wave-uniform
        const int dc = d < CAP ? d : CAP;
        const int mycol = (lane < dc) ? bucket[(size_t)node * CAP + lane] : 0;
        float a0 = 0.f, a1 = 0.f, a2 = 0.f, a3 = 0.f;
        int i = 0;
        for (; i + 4 <= dc; i += 4) {
            const int c0 = __shfl(mycol, i);
            const int c1 = __shfl(mycol, i + 1);
            const int c2 = __shfl(mycol, i + 2);
            const int c3 = __shfl(mycol, i + 3);
            a0 += h[(size_t)c0 * D_OUT + lane];
            a1 += h[(size_t)c1 * D_OUT + lane];
            a2 += h[(size_t)c2 * D_OUT + lane];
            a3 += h[(size_t)c3 * D_OUT + lane];
        }
        for (; i < dc; ++i) {
            const int c = __shfl(mycol, i);
            a0 += h[(size_t)c * D_OUT + lane];
        }
        const float inv = 1.0f / fmaxf((float)d, 1.0f);
        out[(size_t)node * D_OUT + lane] = ((a0 + a1) + (a2 + a3)) * inv;
    }
}

// ---------------------------------------------------------------------------
// Overflow apply: adds pre-scaled h[col]/deg[row] terms (usually zero work).
// ---------------------------------------------------------------------------
__global__ void ovf_apply_kernel(const float* __restrict__ h,
                                 const int* __restrict__ row,
                                 const int* __restrict__ col,
                                 const int* __restrict__ deg,
                                 const int* __restrict__ ovf_list,
                                 const int* __restrict__ ovf_cnt,
                                 float* __restrict__ out,
                                 int ovf_cap) {
    const int cnt = *ovf_cnt < ovf_cap ? *ovf_cnt : ovf_cap;
    const long long n_tasks = (long long)cnt * D_OUT;
    long long t = (long long)blockIdx.x * blockDim.x + threadIdx.x;
    const long long stride = (long long)gridDim.x * blockDim.x;
    for (; t < n_tasks; t += stride) {
        const int k = (int)(t >> 6);
        const int lane = (int)(t & 63);
        const int e = ovf_list[k];
        const int r = row[e];
        const int s = col[e];
        const float inv = 1.0f / fmaxf((float)deg[r], 1.0f);
        atomicAdd(&out[(size_t)r * D_OUT + lane],
                  h[(size_t)s * D_OUT + lane] * inv);
    }
}

// ---------------------------------------------------------------------------
// Fallback path kernels (ws too small): atomic scatter + div.
// ---------------------------------------------------------------------------
__global__ void scatter_kernel(const float* __restrict__ h,
                               const int* __restrict__ row,
                               const int* __restrict__ col,
                               float* __restrict__ out,
                               int* __restrict__ deg,
                               long long n_tasks) {
    long long t = (long long)blockIdx.x * blockDim.x + threadIdx.x;
    const long long stride = (long long)gridDim.x * blockDim.x;
    for (; t < n_tasks; t += stride) {
        const int e = (int)(t >> 6);
        const int c = (int)(t & 63);
        const int r = row[e];
        const int s = col[e];
        atomicAdd(&out[(size_t)r * D_OUT + c], h[(size_t)s * D_OUT + c]);
        if (c == 0) atomicAdd(&deg[r], 1);
    }
}

__global__ void div_kernel(float* __restrict__ out,
                           const int* __restrict__ deg, int n_total) {
    int t = blockIdx.x * blockDim.x + threadIdx.x;
    if (t < n_total) {
        const int node = t >> 6;
        out[t] *= 1.0f / fmaxf((float)deg[node], 1.0f);
    }
}

__global__ void proj_only_kernel(const float* __restrict__ x,
                                 const float* __restrict__ W,
                                 const float* __restrict__ bvec,
                                 float* __restrict__ h, int n_nodes) {
    const int lane = threadIdx.x & 63;
    const int wave = (int)((blockIdx.x * blockDim.x + threadIdx.x) >> 6);
    const int nwaves = (int)((gridDim.x * blockDim.x) >> 6);
    float w[D_IN];
#pragma unroll
    for (int k = 0; k < D_IN; k += 4) {
        float4 t = *(const float4*)&W[lane * D_IN + k];
        w[k] = t.x; w[k + 1] = t.y; w[k + 2] = t.z; w[k + 3] = t.w;
    }
    const float bias = bvec[lane];
    for (int node = wave; node < n_nodes; node += nwaves) {
        const int nu = __builtin_amdgcn_readfirstlane(node);
        const float* xr = &x[(size_t)nu * D_IN];
        float acc = bias;
#pragma unroll
        for (int k = 0; k < D_IN; ++k) acc += xr[k] * w[k];
        h[(size_t)nu * D_OUT + lane] = acc;
    }
}

extern "C" void kernel_launch(void* const* d_in, const int* in_sizes, int n_in,
                              void* d_out, int out_size, void* d_ws, size_t ws_size,
                              hipStream_t stream) {
    const float* x   = (const float*)d_in[0];
    const float* W   = (const float*)d_in[1];
    const float* b   = (const float*)d_in[2];
    const int*   row = (const int*)d_in[3];
    const int*   col = (const int*)d_in[4];
    float* out = (float*)d_out;

    const int n_nodes = in_sizes[0] / D_IN;
    const int n_edges = in_sizes[3];

    // Workspace: h | deg | ovf_cnt(pad 64) | ovf_list | bucket
    char* p = (char*)d_ws;
    float* h = (float*)p;      p += (size_t)n_nodes * D_OUT * sizeof(float);
    int* deg = (int*)p;        p += (size_t)n_nodes * sizeof(int);
    int* ovf_cnt = (int*)p;    p += 64 * sizeof(int);
    int* ovf_list = (int*)p;   p += (size_t)n_edges * sizeof(int);
    int* bucket = (int*)p;     p += (size_t)n_nodes * CAP * sizeof(int);
    const size_t needed = (size_t)(p - (char*)d_ws);

    if (ws_size >= needed) {
        // one memset covers deg + ovf_cnt (contiguous)
        hipMemsetAsync(deg, 0, ((size_t)n_nodes + 64) * sizeof(int), stream);

        prep_kernel<<<PROJ_BLOCKS + BUCKET_BLOCKS, 256, 0, stream>>>(
            x, W, b, h, row, col, deg, bucket, ovf_cnt, ovf_list,
            n_edges, n_nodes, n_edges);

        const int grid = (n_nodes + 3) / 4;   // 4 waves (nodes) per block
        gather_kernel<<<grid, 256, 0, stream>>>(h, deg, bucket, out, n_nodes);

        ovf_apply_kernel<<<256, 256, 0, stream>>>(h, row, col, deg, ovf_list,
                                                  ovf_cnt, out, n_edges);
    } else {
        // fallback: atomic scatter path
        float* hf = (float*)d_ws;
        int* degf = (int*)((char*)d_ws + (size_t)n_nodes * D_OUT * sizeof(float));
        hipMemsetAsync(out, 0, (size_t)out_size * sizeof(float), stream);
        hipMemsetAsync(degf, 0, (size_t)n_nodes * sizeof(int), stream);
        proj_only_kernel<<<1024, 256, 0, stream>>>(x, W, b, hf, n_nodes);
        const long long n_tasks = (long long)n_edges * D_OUT;
        scatter_kernel<<<16384, 256, 0, stream>>>(hf, row, col, out, degf, n_tasks);
        const int n_total = n_nodes * D_OUT;
        div_kernel<<<(n_total + 255) / 256, 256, 0, stream>>>(out, degf, n_total);
    }
}

// Round 4
// 167.953 us; speedup vs baseline: 4.4109x; 4.4109x over previous
//
#include <hip/hip_runtime.h>
#include <hip/hip_bf16.h>

#define D_IN   128
#define D_OUT  64
#define CAP    64          // per-node bucket capacity; overflow handled exactly
#define BUCKET_BLOCKS 512

using frag_ab = __attribute__((ext_vector_type(8))) short;  // 8 bf16
using frag_cd = __attribute__((ext_vector_type(4))) float;  // 4 fp32

static __device__ __forceinline__ short f2bf(float f) {
    union { float f; unsigned u; } v; v.f = f;
    unsigned r = v.u + 0x7FFFu + ((v.u >> 16) & 1u);   // RNE truncate to bf16
    return (short)(r >> 16);
}
static __device__ __forceinline__ float bflo(unsigned w) {
    union { unsigned u; float f; } v; v.u = w << 16; return v.f;
}
static __device__ __forceinline__ float bfhi(unsigned w) {
    union { unsigned u; float f; } v; v.u = w & 0xFFFF0000u; return v.f;
}

// ---------------------------------------------------------------------------
// Fused prep: blocks [0,proj_blocks) do projection via MFMA (wave = 16-node
// tile, bf16 in-register convert, h stored bf16); remaining blocks build the
// per-destination edge buckets.
// ---------------------------------------------------------------------------
__global__ void prep_kernel(const float* __restrict__ x,
                            const float* __restrict__ W,
                            const float* __restrict__ bvec,
                            unsigned short* __restrict__ h,
                            const int* __restrict__ row,
                            const int* __restrict__ col,
                            int* __restrict__ deg,
                            int* __restrict__ bucket,
                            int* __restrict__ ovf_cnt,
                            int* __restrict__ ovf_list,
                            int ovf_cap, int n_nodes, int n_edges,
                            int proj_blocks) {
    if ((int)blockIdx.x >= proj_blocks) {
        // ---- bucket build (grid-stride over edges) ----
        const int stride = BUCKET_BLOCKS * 256;
        for (int e = ((int)blockIdx.x - proj_blocks) * 256 + (int)threadIdx.x;
             e < n_edges; e += stride) {
            const int r = row[e];
            const int c = col[e];
            const int p = atomicAdd(&deg[r], 1);
            if (p < CAP) {
                bucket[(size_t)r * CAP + p] = c;
            } else {
                const int i = atomicAdd(ovf_cnt, 1);
                if (i < ovf_cap) ovf_list[i] = e;
            }
        }
        return;
    }

    // ---- projection: one wave = one 16-node tile, N=64 via 4 n-tiles ----
    const int lane = (int)threadIdx.x & 63;
    const int wid  = (int)((blockIdx.x * blockDim.x + threadIdx.x) >> 6);
    const int m    = lane & 15;   // A row (node) / B row (channel) / C col
    const int quad = lane >> 4;   // k-subchunk selector

    // B fragments: Bf[kk][nt][j] = W[nt*16+m][kk*32 + quad*8 + j]
    frag_ab Bf[4][4];
#pragma unroll
    for (int kk = 0; kk < 4; ++kk) {
#pragma unroll
        for (int nt = 0; nt < 4; ++nt) {
            const float* wp = W + (size_t)(nt * 16 + m) * D_IN + kk * 32 + quad * 8;
            const float4 w0 = *(const float4*)wp;
            const float4 w1 = *(const float4*)(wp + 4);
            frag_ab f;
            f[0] = f2bf(w0.x); f[1] = f2bf(w0.y); f[2] = f2bf(w0.z); f[3] = f2bf(w0.w);
            f[4] = f2bf(w1.x); f[5] = f2bf(w1.y); f[6] = f2bf(w1.z); f[7] = f2bf(w1.w);
            Bf[kk][nt] = f;
        }
    }

    const int node_base = wid * 16;
    if (node_base >= n_nodes) return;
    int arow = node_base + m;
    if (arow > n_nodes - 1) arow = n_nodes - 1;   // clamp for partial tiles

    frag_cd acc[4];
#pragma unroll
    for (int nt = 0; nt < 4; ++nt) {
        const float bb = bvec[nt * 16 + m];       // col = lane&15 -> channel
        acc[nt][0] = bb; acc[nt][1] = bb; acc[nt][2] = bb; acc[nt][3] = bb;
    }

#pragma unroll
    for (int kk = 0; kk < 4; ++kk) {
        const float* xp = x + (size_t)arow * D_IN + kk * 32 + quad * 8;
        const float4 x0 = *(const float4*)xp;
        const float4 x1 = *(const float4*)(xp + 4);
        frag_ab A;
        A[0] = f2bf(x0.x); A[1] = f2bf(x0.y); A[2] = f2bf(x0.z); A[3] = f2bf(x0.w);
        A[4] = f2bf(x1.x); A[5] = f2bf(x1.y); A[6] = f2bf(x1.z); A[7] = f2bf(x1.w);
#pragma unroll
        for (int nt = 0; nt < 4; ++nt)
            acc[nt] = __builtin_amdgcn_mfma_f32_16x16x32_bf16(A, Bf[kk][nt],
                                                              acc[nt], 0, 0, 0);
    }

    // C/D: col = lane&15 (channel within n-tile), row = quad*4 + reg (node)
#pragma unroll
    for (int nt = 0; nt < 4; ++nt) {
#pragma unroll
        for (int r = 0; r < 4; ++r) {
            const int node = node_base + quad * 4 + r;
            if (node < n_nodes)
                h[(size_t)node * D_OUT + nt * 16 + m] =
                    (unsigned short)f2bf(acc[nt][r]);
        }
    }
}

// ---------------------------------------------------------------------------
// Gather with fused mean over bf16 h: one wave per node. Half-wave 0 handles
// even bucket entries, half-wave 1 odd; each lane reads one bfloat162 word
// (2 channels) -> 2x256B coalesced per instruction. shfl-combine halves.
// ---------------------------------------------------------------------------
__global__ void gather_kernel(const unsigned short* __restrict__ h,
                              const int* __restrict__ deg,
                              const int* __restrict__ bucket,
                              float* __restrict__ out,
                              int n_nodes) {
    const int lane  = (int)threadIdx.x & 63;
    const int half  = lane >> 5;        // 0 / 1
    const int cpair = lane & 31;        // channel pair: channels 2c, 2c+1
    int wave = (int)((blockIdx.x * blockDim.x + threadIdx.x) >> 6);
    const int nwaves = (int)((gridDim.x * blockDim.x) >> 6);
    const unsigned* h32 = (const unsigned*)h;

    for (int node = wave; node < n_nodes; node += nwaves) {
        const int d  = deg[node];                       // wave-uniform
        const int dc = d < CAP ? d : CAP;
        const int mycol = (lane < dc) ? bucket[(size_t)node * CAP + lane] : 0;
        const int npairs = (dc + 1) >> 1;

        float a0 = 0.f, a1 = 0.f, b0 = 0.f, b1 = 0.f;
        int p = 0;
        for (; p + 2 <= npairs; p += 2) {
            const int eA0 = __shfl(mycol, 2 * p);
            const int eA1 = __shfl(mycol, 2 * p + 1);
            const int eB0 = __shfl(mycol, 2 * p + 2);
            const int eB1 = __shfl(mycol, 2 * p + 3);
            const int iA = half ? eA1 : eA0;
            const int iB = half ? eB1 : eB0;
            const bool vA = (2 * p + half) < dc;
            const bool vB = (2 * p + 2 + half) < dc;
            const unsigned wA = vA ? h32[(size_t)iA * 32 + cpair] : 0u;
            const unsigned wB = vB ? h32[(size_t)iB * 32 + cpair] : 0u;
            a0 += bflo(wA); a1 += bfhi(wA);
            b0 += bflo(wB); b1 += bfhi(wB);
        }
        for (; p < npairs; ++p) {
            const int e0 = __shfl(mycol, 2 * p);
            const int e1 = __shfl(mycol, 2 * p + 1);
            const int idx = half ? e1 : e0;
            const bool v = (2 * p + half) < dc;
            const unsigned wv = v ? h32[(size_t)idx * 32 + cpair] : 0u;
            a0 += bflo(wv); a1 += bfhi(wv);
        }
        a0 += b0; a1 += b1;
        const float s0 = a0 + __shfl_xor(a0, 32);
        const float s1 = a1 + __shfl_xor(a1, 32);
        if (half == 0) {
            const float inv = 1.0f / fmaxf((float)d, 1.0f);
            float2 v; v.x = s0 * inv; v.y = s1 * inv;
            *(float2*)(out + (size_t)node * D_OUT + 2 * cpair) = v;
        }
    }
}

// ---------------------------------------------------------------------------
// Overflow apply (normally zero work): adds pre-scaled h[col]/deg[row].
// ---------------------------------------------------------------------------
__global__ void ovf_apply_kernel(const unsigned short* __restrict__ h,
                                 const int* __restrict__ row,
                                 const int* __restrict__ col,
                                 const int* __restrict__ deg,
                                 const int* __restrict__ ovf_list,
                                 const int* __restrict__ ovf_cnt,
                                 float* __restrict__ out,
                                 int ovf_cap) {
    const int cnt = *ovf_cnt < ovf_cap ? *ovf_cnt : ovf_cap;
    const long long n_tasks = (long long)cnt * D_OUT;
    long long t = (long long)blockIdx.x * blockDim.x + threadIdx.x;
    const long long stride = (long long)gridDim.x * blockDim.x;
    for (; t < n_tasks; t += stride) {
        const int k = (int)(t >> 6);
        const int lane = (int)(t & 63);
        const int e = ovf_list[k];
        const int r = row[e];
        const int s = col[e];
        union { unsigned u; float f; } v;
        v.u = ((unsigned)h[(size_t)s * D_OUT + lane]) << 16;
        const float inv = 1.0f / fmaxf((float)deg[r], 1.0f);
        atomicAdd(&out[(size_t)r * D_OUT + lane], v.f * inv);
    }
}

// ---------------------------------------------------------------------------
// Fallback path (ws too small): fp32 h + atomic scatter + div.
// ---------------------------------------------------------------------------
__global__ void proj_only_kernel(const float* __restrict__ x,
                                 const float* __restrict__ W,
                                 const float* __restrict__ bvec,
                                 float* __restrict__ h, int n_nodes) {
    const int lane = (int)threadIdx.x & 63;
    const int wave = (int)((blockIdx.x * blockDim.x + threadIdx.x) >> 6);
    const int nwaves = (int)((gridDim.x * blockDim.x) >> 6);
    const float bias = bvec[lane];
    for (int node = wave; node < n_nodes; node += nwaves) {
        const float* xr = &x[(size_t)node * D_IN];
        float acc = bias;
#pragma unroll
        for (int k = 0; k < D_IN; ++k) acc += xr[k] * W[lane * D_IN + k];
        h[(size_t)node * D_OUT + lane] = acc;
    }
}

__global__ void scatter_kernel(const float* __restrict__ h,
                               const int* __restrict__ row,
                               const int* __restrict__ col,
                               float* __restrict__ out,
                               int* __restrict__ deg,
                               long long n_tasks) {
    long long t = (long long)blockIdx.x * blockDim.x + threadIdx.x;
    const long long stride = (long long)gridDim.x * blockDim.x;
    for (; t < n_tasks; t += stride) {
        const int e = (int)(t >> 6);
        const int c = (int)(t & 63);
        atomicAdd(&out[(size_t)row[e] * D_OUT + c], h[(size_t)col[e] * D_OUT + c]);
        if (c == 0) atomicAdd(&deg[row[e]], 1);
    }
}

__global__ void div_kernel(float* __restrict__ out,
                           const int* __restrict__ deg, int n_total) {
    int t = blockIdx.x * blockDim.x + threadIdx.x;
    if (t < n_total) {
        out[t] *= 1.0f / fmaxf((float)deg[t >> 6], 1.0f);
    }
}

extern "C" void kernel_launch(void* const* d_in, const int* in_sizes, int n_in,
                              void* d_out, int out_size, void* d_ws, size_t ws_size,
                              hipStream_t stream) {
    const float* x   = (const float*)d_in[0];
    const float* W   = (const float*)d_in[1];
    const float* b   = (const float*)d_in[2];
    const int*   row = (const int*)d_in[3];
    const int*   col = (const int*)d_in[4];
    float* out = (float*)d_out;

    const int n_nodes = in_sizes[0] / D_IN;
    const int n_edges = in_sizes[3];

    // Workspace: h(bf16) | deg | ovf_cnt(pad 64) | ovf_list | bucket
    char* p = (char*)d_ws;
    unsigned short* h = (unsigned short*)p;
    p += (size_t)n_nodes * D_OUT * sizeof(unsigned short);
    int* deg = (int*)p;        p += (size_t)n_nodes * sizeof(int);
    int* ovf_cnt = (int*)p;    p += 64 * sizeof(int);
    int* ovf_list = (int*)p;   p += (size_t)n_edges * sizeof(int);
    int* bucket = (int*)p;     p += (size_t)n_nodes * CAP * sizeof(int);
    const size_t needed = (size_t)(p - (char*)d_ws);

    if (ws_size >= needed) {
        hipMemsetAsync(deg, 0, ((size_t)n_nodes + 64) * sizeof(int), stream);

        const int tiles = (n_nodes + 15) / 16;        // waves for proj
        const int proj_blocks = (tiles + 3) / 4;      // 4 waves / block
        prep_kernel<<<proj_blocks + BUCKET_BLOCKS, 256, 0, stream>>>(
            x, W, b, h, row, col, deg, bucket, ovf_cnt, ovf_list,
            n_edges, n_nodes, n_edges, proj_blocks);

        const int grid = (n_nodes + 3) / 4;           // 1 wave / node
        gather_kernel<<<grid, 256, 0, stream>>>(h, deg, bucket, out, n_nodes);

        ovf_apply_kernel<<<256, 256, 0, stream>>>(h, row, col, deg, ovf_list,
                                                  ovf_cnt, out, n_edges);
    } else {
        // fallback: fp32 h + atomic scatter
        float* hf = (float*)d_ws;
        int* degf = (int*)((char*)d_ws + (size_t)n_nodes * D_OUT * sizeof(float));
        hipMemsetAsync(out, 0, (size_t)out_size * sizeof(float), stream);
        hipMemsetAsync(degf, 0, (size_t)n_nodes * sizeof(int), stream);
        proj_only_kernel<<<1024, 256, 0, stream>>>(x, W, b, hf, n_nodes);
        const long long n_tasks = (long long)n_edges * D_OUT;
        scatter_kernel<<<16384, 256, 0, stream>>>(hf, row, col, out, degf, n_tasks);
        const int n_total = n_nodes * D_OUT;
        div_kernel<<<(n_total + 255) / 256, 256, 0, stream>>>(out, degf, n_total);
    }
}

// Round 5
// 163.006 us; speedup vs baseline: 4.5448x; 1.0303x over previous
//
#include <hip/hip_runtime.h>
#include <hip/hip_bf16.h>

#define D_IN   128
#define D_OUT  64
#define CAP    64          // per-node bucket capacity; overflow handled exactly
#define MAX_USHORT_NODES 65536

using frag_ab = __attribute__((ext_vector_type(8))) short;  // 8 bf16
using frag_cd = __attribute__((ext_vector_type(4))) float;  // 4 fp32

static __device__ __forceinline__ short f2bf(float f) {
    union { float f; unsigned u; } v; v.f = f;
    unsigned r = v.u + 0x7FFFu + ((v.u >> 16) & 1u);   // RNE truncate to bf16
    return (short)(r >> 16);
}
static __device__ __forceinline__ float bflo(unsigned w) {
    union { unsigned u; float f; } v; v.u = w << 16; return v.f;
}
static __device__ __forceinline__ float bfhi(unsigned w) {
    union { unsigned u; float f; } v; v.u = w & 0xFFFF0000u; return v.f;
}

// ---------------------------------------------------------------------------
// Projection via MFMA: wave = 16-node tile, grid-stride (2 tiles/wave).
// A = x (16 nodes x 128k), B = W (64 ch x 128k), h stored bf16.
// Layouts (m89/m91-verified): A[m=lane&15][k=quad*8+j]; C/D col=lane&15,
// row=quad*4+reg.
// ---------------------------------------------------------------------------
__global__ void proj_kernel(const float* __restrict__ x,
                            const float* __restrict__ W,
                            const float* __restrict__ bvec,
                            unsigned short* __restrict__ h,
                            int n_nodes) {
    const int lane = (int)threadIdx.x & 63;
    const int wid  = (int)((blockIdx.x * blockDim.x + threadIdx.x) >> 6);
    const int nwaves = (int)((gridDim.x * blockDim.x) >> 6);
    const int m    = lane & 15;
    const int quad = lane >> 4;

    // B fragments: Bf[kk][nt][j] = W[nt*16+m][kk*32 + quad*8 + j]
    frag_ab Bf[4][4];
#pragma unroll
    for (int kk = 0; kk < 4; ++kk) {
#pragma unroll
        for (int nt = 0; nt < 4; ++nt) {
            const float* wp = W + (size_t)(nt * 16 + m) * D_IN + kk * 32 + quad * 8;
            const float4 w0 = *(const float4*)wp;
            const float4 w1 = *(const float4*)(wp + 4);
            frag_ab f;
            f[0] = f2bf(w0.x); f[1] = f2bf(w0.y); f[2] = f2bf(w0.z); f[3] = f2bf(w0.w);
            f[4] = f2bf(w1.x); f[5] = f2bf(w1.y); f[6] = f2bf(w1.z); f[7] = f2bf(w1.w);
            Bf[kk][nt] = f;
        }
    }
    float bb[4];
#pragma unroll
    for (int nt = 0; nt < 4; ++nt) bb[nt] = bvec[nt * 16 + m];

    const int ntiles = (n_nodes + 15) / 16;
    for (int tile = wid; tile < ntiles; tile += nwaves) {
        const int node_base = tile * 16;
        int arow = node_base + m;
        if (arow > n_nodes - 1) arow = n_nodes - 1;

        // issue all 8 x-loads up front (independent -> MLP)
        float4 xv[8];
        const float* xr = x + (size_t)arow * D_IN + quad * 8;
#pragma unroll
        for (int kk = 0; kk < 4; ++kk) {
            xv[2 * kk]     = *(const float4*)(xr + kk * 32);
            xv[2 * kk + 1] = *(const float4*)(xr + kk * 32 + 4);
        }

        frag_cd acc[4];
#pragma unroll
        for (int nt = 0; nt < 4; ++nt) {
            acc[nt][0] = bb[nt]; acc[nt][1] = bb[nt];
            acc[nt][2] = bb[nt]; acc[nt][3] = bb[nt];
        }
#pragma unroll
        for (int kk = 0; kk < 4; ++kk) {
            const float4 x0 = xv[2 * kk], x1 = xv[2 * kk + 1];
            frag_ab A;
            A[0] = f2bf(x0.x); A[1] = f2bf(x0.y); A[2] = f2bf(x0.z); A[3] = f2bf(x0.w);
            A[4] = f2bf(x1.x); A[5] = f2bf(x1.y); A[6] = f2bf(x1.z); A[7] = f2bf(x1.w);
#pragma unroll
            for (int nt = 0; nt < 4; ++nt)
                acc[nt] = __builtin_amdgcn_mfma_f32_16x16x32_bf16(A, Bf[kk][nt],
                                                                  acc[nt], 0, 0, 0);
        }
#pragma unroll
        for (int nt = 0; nt < 4; ++nt) {
#pragma unroll
            for (int r = 0; r < 4; ++r) {
                const int node = node_base + quad * 4 + r;
                if (node < n_nodes)
                    h[(size_t)node * D_OUT + nt * 16 + m] =
                        (unsigned short)f2bf(acc[nt][r]);
            }
        }
    }
}

// ---------------------------------------------------------------------------
// Bucket build: one thread per edge (single atomic round-trip per thread).
// ushort entries (requires n_nodes <= 65536).
// ---------------------------------------------------------------------------
__global__ void bucket_kernel(const int* __restrict__ row,
                              const int* __restrict__ col,
                              int* __restrict__ deg,
                              unsigned short* __restrict__ bucket,
                              int* __restrict__ ovf_cnt,
                              int* __restrict__ ovf_list,
                              int ovf_cap, int n_edges) {
    const int e = (int)(blockIdx.x * blockDim.x + threadIdx.x);
    if (e >= n_edges) return;
    const int r = row[e];
    const int c = col[e];
    const int p = atomicAdd(&deg[r], 1);
    if (p < CAP) {
        bucket[(size_t)r * CAP + p] = (unsigned short)c;
    } else {
        const int i = atomicAdd(ovf_cnt, 1);
        if (i < ovf_cap) ovf_list[i] = e;
    }
}

// ---------------------------------------------------------------------------
// Gather with fused mean: wave per node; quarter-wave per bucket entry.
// Lane (q=lane>>4, j=lane&15) reads h64[idx*16+j] (uint2 = 4 bf16 channels)
// -> one load instruction covers 4 edges x 128B coalesced. deg/bucket for
// the NEXT node prefetched over the current node's h-load latency.
// ---------------------------------------------------------------------------
__global__ void gather_kernel(const uint2* __restrict__ h64,
                              const int* __restrict__ deg,
                              const unsigned short* __restrict__ bucket,
                              float4* __restrict__ out4,
                              int n_nodes) {
    const int lane = (int)threadIdx.x & 63;
    const int q = lane >> 4;
    const int j = lane & 15;
    const int wave = (int)((blockIdx.x * blockDim.x + threadIdx.x) >> 6);
    const int nwaves = (int)((gridDim.x * blockDim.x) >> 6);

    int node = wave;
    if (node >= n_nodes) return;
    int d_nxt = deg[node];
    int my_nxt = (int)bucket[(size_t)node * CAP + lane];  // full CAP row, unconditional

    while (node < n_nodes) {
        const int d = d_nxt;
        const int mycol = my_nxt;
        const int nxt = node + nwaves;
        if (nxt < n_nodes) {
            d_nxt = deg[nxt];
            my_nxt = (int)bucket[(size_t)nxt * CAP + lane];
        }

        const int dc = d < CAP ? d : CAP;
        const int ngr = (dc + 3) >> 2;
        float a0 = 0.f, a1 = 0.f, a2 = 0.f, a3 = 0.f;
        float b0 = 0.f, b1 = 0.f, b2 = 0.f, b3 = 0.f;
        int g = 0;
        for (; g + 2 <= ngr; g += 2) {
            const int iA = __shfl(mycol, 4 * g + q);
            const int iB = __shfl(mycol, 4 * g + 4 + q);
            uint2 wA = h64[(size_t)iA * 16 + j];
            uint2 wB = h64[(size_t)iB * 16 + j];
            if (4 * g + q >= dc)     { wA.x = 0u; wA.y = 0u; }
            if (4 * g + 4 + q >= dc) { wB.x = 0u; wB.y = 0u; }
            a0 += bflo(wA.x); a1 += bfhi(wA.x); a2 += bflo(wA.y); a3 += bfhi(wA.y);
            b0 += bflo(wB.x); b1 += bfhi(wB.x); b2 += bflo(wB.y); b3 += bfhi(wB.y);
        }
        for (; g < ngr; ++g) {
            const int iA = __shfl(mycol, 4 * g + q);
            uint2 wA = h64[(size_t)iA * 16 + j];
            if (4 * g + q >= dc) { wA.x = 0u; wA.y = 0u; }
            a0 += bflo(wA.x); a1 += bfhi(wA.x); a2 += bflo(wA.y); a3 += bfhi(wA.y);
        }
        a0 += b0; a1 += b1; a2 += b2; a3 += b3;
        a0 += __shfl_xor(a0, 16); a0 += __shfl_xor(a0, 32);
        a1 += __shfl_xor(a1, 16); a1 += __shfl_xor(a1, 32);
        a2 += __shfl_xor(a2, 16); a2 += __shfl_xor(a2, 32);
        a3 += __shfl_xor(a3, 16); a3 += __shfl_xor(a3, 32);
        if (q == 0) {
            const float inv = 1.0f / fmaxf((float)d, 1.0f);
            float4 o;
            o.x = a0 * inv; o.y = a1 * inv; o.z = a2 * inv; o.w = a3 * inv;
            out4[(size_t)node * (D_OUT / 4) + j] = o;
        }
        node = nxt;
    }
}

// ---------------------------------------------------------------------------
// Overflow apply (normally zero work): adds pre-scaled h[col]/deg[row].
// ---------------------------------------------------------------------------
__global__ void ovf_apply_kernel(const unsigned short* __restrict__ h,
                                 const int* __restrict__ row,
                                 const int* __restrict__ col,
                                 const int* __restrict__ deg,
                                 const int* __restrict__ ovf_list,
                                 const int* __restrict__ ovf_cnt,
                                 float* __restrict__ out,
                                 int ovf_cap) {
    const int cnt = *ovf_cnt < ovf_cap ? *ovf_cnt : ovf_cap;
    const long long n_tasks = (long long)cnt * D_OUT;
    long long t = (long long)blockIdx.x * blockDim.x + threadIdx.x;
    const long long stride = (long long)gridDim.x * blockDim.x;
    for (; t < n_tasks; t += stride) {
        const int k = (int)(t >> 6);
        const int lane = (int)(t & 63);
        const int e = ovf_list[k];
        const int r = row[e];
        const int s = col[e];
        union { unsigned u; float f; } v;
        v.u = ((unsigned)h[(size_t)s * D_OUT + lane]) << 16;
        const float inv = 1.0f / fmaxf((float)deg[r], 1.0f);
        atomicAdd(&out[(size_t)r * D_OUT + lane], v.f * inv);
    }
}

// ---------------------------------------------------------------------------
// Fallback path (ws too small or n_nodes > 65536): fp32 h + atomic scatter.
// ---------------------------------------------------------------------------
__global__ void proj_only_kernel(const float* __restrict__ x,
                                 const float* __restrict__ W,
                                 const float* __restrict__ bvec,
                                 float* __restrict__ h, int n_nodes) {
    const int lane = (int)threadIdx.x & 63;
    const int wave = (int)((blockIdx.x * blockDim.x + threadIdx.x) >> 6);
    const int nwaves = (int)((gridDim.x * blockDim.x) >> 6);
    const float bias = bvec[lane];
    for (int node = wave; node < n_nodes; node += nwaves) {
        const float* xr = &x[(size_t)node * D_IN];
        float acc = bias;
#pragma unroll
        for (int k = 0; k < D_IN; ++k) acc += xr[k] * W[lane * D_IN + k];
        h[(size_t)node * D_OUT + lane] = acc;
    }
}

__global__ void scatter_kernel(const float* __restrict__ h,
                               const int* __restrict__ row,
                               const int* __restrict__ col,
                               float* __restrict__ out,
                               int* __restrict__ deg,
                               long long n_tasks) {
    long long t = (long long)blockIdx.x * blockDim.x + threadIdx.x;
    const long long stride = (long long)gridDim.x * blockDim.x;
    for (; t < n_tasks; t += stride) {
        const int e = (int)(t >> 6);
        const int c = (int)(t & 63);
        atomicAdd(&out[(size_t)row[e] * D_OUT + c], h[(size_t)col[e] * D_OUT + c]);
        if (c == 0) atomicAdd(&deg[row[e]], 1);
    }
}

__global__ void div_kernel(float* __restrict__ out,
                           const int* __restrict__ deg, int n_total) {
    int t = blockIdx.x * blockDim.x + threadIdx.x;
    if (t < n_total) {
        out[t] *= 1.0f / fmaxf((float)deg[t >> 6], 1.0f);
    }
}

extern "C" void kernel_launch(void* const* d_in, const int* in_sizes, int n_in,
                              void* d_out, int out_size, void* d_ws, size_t ws_size,
                              hipStream_t stream) {
    const float* x   = (const float*)d_in[0];
    const float* W   = (const float*)d_in[1];
    const float* b   = (const float*)d_in[2];
    const int*   row = (const int*)d_in[3];
    const int*   col = (const int*)d_in[4];
    float* out = (float*)d_out;

    const int n_nodes = in_sizes[0] / D_IN;
    const int n_edges = in_sizes[3];

    // Workspace: h(bf16) | deg | ovf_cnt(pad 64) | ovf_list | bucket(ushort)
    char* p = (char*)d_ws;
    unsigned short* h = (unsigned short*)p;
    p += (size_t)n_nodes * D_OUT * sizeof(unsigned short);
    int* deg = (int*)p;        p += (size_t)n_nodes * sizeof(int);
    int* ovf_cnt = (int*)p;    p += 64 * sizeof(int);
    int* ovf_list = (int*)p;   p += (size_t)n_edges * sizeof(int);
    unsigned short* bucket = (unsigned short*)p;
    p += (size_t)n_nodes * CAP * sizeof(unsigned short);
    const size_t needed = (size_t)(p - (char*)d_ws);

    if (ws_size >= needed && n_nodes <= MAX_USHORT_NODES) {
        hipMemsetAsync(deg, 0, ((size_t)n_nodes + 64) * sizeof(int), stream);

        // 1) projection: 391 blocks x 4 waves = 1564 waves, 2 tiles each
        const int ntiles = (n_nodes + 15) / 16;
        const int proj_blocks = (ntiles + 7) / 8;   // 2 tiles per wave
        proj_kernel<<<proj_blocks, 256, 0, stream>>>(x, W, b, h, n_nodes);

        // 2) bucket build: 1 thread per edge
        bucket_kernel<<<(n_edges + 255) / 256, 256, 0, stream>>>(
            row, col, deg, bucket, ovf_cnt, ovf_list, n_edges, n_edges);

        // 3) gather: 1 wave per node
        const int grid = (n_nodes + 3) / 4;
        gather_kernel<<<grid, 256, 0, stream>>>((const uint2*)h, deg, bucket,
                                                (float4*)out, n_nodes);

        // 4) overflow (zero work in practice)
        ovf_apply_kernel<<<256, 256, 0, stream>>>(h, row, col, deg, ovf_list,
                                                  ovf_cnt, out, n_edges);
    } else {
        // fallback: fp32 h + atomic scatter
        float* hf = (float*)d_ws;
        int* degf = (int*)((char*)d_ws + (size_t)n_nodes * D_OUT * sizeof(float));
        hipMemsetAsync(out, 0, (size_t)out_size * sizeof(float), stream);
        hipMemsetAsync(degf, 0, (size_t)n_nodes * sizeof(int), stream);
        proj_only_kernel<<<1024, 256, 0, stream>>>(x, W, b, hf, n_nodes);
        const long long n_tasks = (long long)n_edges * D_OUT;
        scatter_kernel<<<16384, 256, 0, stream>>>(hf, row, col, out, degf, n_tasks);
        const int n_total = n_nodes * D_OUT;
        div_kernel<<<(n_total + 255) / 256, 256, 0, stream>>>(out, degf, n_total);
    }
}

// Round 6
// 135.120 us; speedup vs baseline: 5.4827x; 1.2064x over previous
//
#include <hip/hip_runtime.h>
#include <hip/hip_bf16.h>

#define D_IN   128
#define D_OUT  64
#define CAP    64          // per-node bucket capacity; overflow handled exactly
#define MAX_USHORT_NODES 65536
#define BIN_SHIFT 8        // 256 node ids per bin
#define MAX_BINS  256
#define BIN_CAP   8192     // scratch slots per bin (expected ~4082; exact via ovfA)
#define P1_BLOCKS 256
#define P1_THREADS 512
#define P2_THREADS 512

using frag_ab = __attribute__((ext_vector_type(8))) short;  // 8 bf16
using frag_cd = __attribute__((ext_vector_type(4))) float;  // 4 fp32

static __device__ __forceinline__ short f2bf(float f) {
    union { float f; unsigned u; } v; v.f = f;
    unsigned r = v.u + 0x7FFFu + ((v.u >> 16) & 1u);   // RNE truncate to bf16
    return (short)(r >> 16);
}
static __device__ __forceinline__ float bflo(unsigned w) {
    union { unsigned u; float f; } v; v.u = w << 16; return v.f;
}
static __device__ __forceinline__ float bfhi(unsigned w) {
    union { unsigned u; float f; } v; v.u = w & 0xFFFF0000u; return v.f;
}

// ---------------------------------------------------------------------------
// Projection via MFMA (unchanged from R5): wave = 16-node tile, grid-stride.
// ---------------------------------------------------------------------------
__global__ void proj_kernel(const float* __restrict__ x,
                            const float* __restrict__ W,
                            const float* __restrict__ bvec,
                            unsigned short* __restrict__ h,
                            int n_nodes) {
    const int lane = (int)threadIdx.x & 63;
    const int wid  = (int)((blockIdx.x * blockDim.x + threadIdx.x) >> 6);
    const int nwaves = (int)((gridDim.x * blockDim.x) >> 6);
    const int m    = lane & 15;
    const int quad = lane >> 4;

    frag_ab Bf[4][4];
#pragma unroll
    for (int kk = 0; kk < 4; ++kk) {
#pragma unroll
        for (int nt = 0; nt < 4; ++nt) {
            const float* wp = W + (size_t)(nt * 16 + m) * D_IN + kk * 32 + quad * 8;
            const float4 w0 = *(const float4*)wp;
            const float4 w1 = *(const float4*)(wp + 4);
            frag_ab f;
            f[0] = f2bf(w0.x); f[1] = f2bf(w0.y); f[2] = f2bf(w0.z); f[3] = f2bf(w0.w);
            f[4] = f2bf(w1.x); f[5] = f2bf(w1.y); f[6] = f2bf(w1.z); f[7] = f2bf(w1.w);
            Bf[kk][nt] = f;
        }
    }
    float bb[4];
#pragma unroll
    for (int nt = 0; nt < 4; ++nt) bb[nt] = bvec[nt * 16 + m];

    const int ntiles = (n_nodes + 15) / 16;
    for (int tile = wid; tile < ntiles; tile += nwaves) {
        const int node_base = tile * 16;
        int arow = node_base + m;
        if (arow > n_nodes - 1) arow = n_nodes - 1;

        float4 xv[8];
        const float* xr = x + (size_t)arow * D_IN + quad * 8;
#pragma unroll
        for (int kk = 0; kk < 4; ++kk) {
            xv[2 * kk]     = *(const float4*)(xr + kk * 32);
            xv[2 * kk + 1] = *(const float4*)(xr + kk * 32 + 4);
        }

        frag_cd acc[4];
#pragma unroll
        for (int nt = 0; nt < 4; ++nt) {
            acc[nt][0] = bb[nt]; acc[nt][1] = bb[nt];
            acc[nt][2] = bb[nt]; acc[nt][3] = bb[nt];
        }
#pragma unroll
        for (int kk = 0; kk < 4; ++kk) {
            const float4 x0 = xv[2 * kk], x1 = xv[2 * kk + 1];
            frag_ab A;
            A[0] = f2bf(x0.x); A[1] = f2bf(x0.y); A[2] = f2bf(x0.z); A[3] = f2bf(x0.w);
            A[4] = f2bf(x1.x); A[5] = f2bf(x1.y); A[6] = f2bf(x1.z); A[7] = f2bf(x1.w);
#pragma unroll
            for (int nt = 0; nt < 4; ++nt)
                acc[nt] = __builtin_amdgcn_mfma_f32_16x16x32_bf16(A, Bf[kk][nt],
                                                                  acc[nt], 0, 0, 0);
        }
#pragma unroll
        for (int nt = 0; nt < 4; ++nt) {
#pragma unroll
            for (int r = 0; r < 4; ++r) {
                const int node = node_base + quad * 4 + r;
                if (node < n_nodes)
                    h[(size_t)node * D_OUT + nt * 16 + m] =
                        (unsigned short)f2bf(acc[nt][r]);
            }
        }
    }
}

// ---------------------------------------------------------------------------
// Pass 1: per-block LDS histogram over bins -> claim contiguous bin ranges
// with ONE global atomic per (block,bin) -> scatter packed (r_lo | c<<8)
// records into bin scratch. cursor is line-padded (stride 16 ints).
// ---------------------------------------------------------------------------
__global__ __launch_bounds__(P1_THREADS)
void binpass1_kernel(const int* __restrict__ row, const int* __restrict__ col,
                     unsigned* __restrict__ scratch, int* __restrict__ cursor,
                     int* __restrict__ ovfA_cnt, unsigned* __restrict__ ovfA_list,
                     int ovfA_cap, int n_edges, int n_bins) {
    __shared__ int hist[MAX_BINS];
    __shared__ int base[MAX_BINS];
    const int per = (n_edges + P1_BLOCKS - 1) / P1_BLOCKS;
    const int e0 = (int)blockIdx.x * per;
    const int e1 = min(e0 + per, n_edges);

    for (int i = threadIdx.x; i < n_bins; i += P1_THREADS) hist[i] = 0;
    __syncthreads();
    for (int e = e0 + (int)threadIdx.x; e < e1; e += P1_THREADS)
        atomicAdd(&hist[row[e] >> BIN_SHIFT], 1);
    __syncthreads();
    for (int i = threadIdx.x; i < n_bins; i += P1_THREADS) {
        const int hcnt = hist[i];
        base[i] = hcnt > 0 ? atomicAdd(&cursor[i * 16], hcnt) : 0;
        hist[i] = 0;
    }
    __syncthreads();
    for (int e = e0 + (int)threadIdx.x; e < e1; e += P1_THREADS) {
        const int r = row[e];
        const int c = col[e];
        const int bn = r >> BIN_SHIFT;
        const int loc = atomicAdd(&hist[bn], 1);
        const int off = base[bn] + loc;
        if (off < BIN_CAP) {
            scratch[(size_t)bn * BIN_CAP + off] =
                (unsigned)(r & 255) | ((unsigned)c << 8);
        } else {
            const int k = atomicAdd(ovfA_cnt, 1);
            if (k < ovfA_cap) ovfA_list[k] = (unsigned)r | ((unsigned)c << 16);
        }
    }
}

// ---------------------------------------------------------------------------
// Pass 2: one block per bin. Build exact deg + bucket rows in LDS (atomics
// stay on-CU), then stream out with coalesced uint4 stores.
// ---------------------------------------------------------------------------
__global__ __launch_bounds__(P2_THREADS)
void binpass2_kernel(const unsigned* __restrict__ scratch,
                     const int* __restrict__ cursor,
                     int* __restrict__ deg, unsigned short* __restrict__ bucket,
                     int* __restrict__ ovfB_cnt, unsigned* __restrict__ ovfB_list,
                     int ovfB_cap, int n_nodes) {
    __shared__ int ldeg[256];
    __shared__ unsigned short lbuck[256 * CAP];   // 32 KB
    const int bin = (int)blockIdx.x;
    const int node0 = bin << BIN_SHIFT;
    const int nrows = min(256, n_nodes - node0);
    int cnt = cursor[bin * 16]; if (cnt > BIN_CAP) cnt = BIN_CAP;

    for (int i = threadIdx.x; i < 256; i += P2_THREADS) ldeg[i] = 0;
    __syncthreads();
    for (int i = threadIdx.x; i < cnt; i += P2_THREADS) {
        const unsigned rec = scratch[(size_t)bin * BIN_CAP + i];
        const int rl = rec & 255;
        const int c  = (int)(rec >> 8);
        const int s = atomicAdd(&ldeg[rl], 1);
        if (s < CAP) {
            lbuck[(rl << 6) + s] = (unsigned short)c;
        } else {
            const int k = atomicAdd(ovfB_cnt, 1);
            if (k < ovfB_cap)
                ovfB_list[k] = (unsigned)(node0 + rl) | ((unsigned)c << 16);
        }
    }
    __syncthreads();
    for (int i = threadIdx.x; i < nrows; i += P2_THREADS) deg[node0 + i] = ldeg[i];
    // bucket rows: nrows * 128 B, coalesced uint4
    uint4* dst = (uint4*)(bucket + (size_t)node0 * CAP);
    const uint4* src = (const uint4*)lbuck;
    const int nu4 = nrows * 8;
    for (int i = threadIdx.x; i < nu4; i += P2_THREADS) dst[i] = src[i];
}

// ---------------------------------------------------------------------------
// Fix deg for pass1-overflow edges (normally zero work).
// ---------------------------------------------------------------------------
__global__ void degfix_kernel(const unsigned* __restrict__ ovfA_list,
                              const int* __restrict__ ovfA_cnt, int ovfA_cap,
                              int* __restrict__ deg) {
    int cnt = *ovfA_cnt; if (cnt > ovfA_cap) cnt = ovfA_cap;
    for (int t = (int)(blockIdx.x * blockDim.x + threadIdx.x); t < cnt;
         t += (int)(gridDim.x * blockDim.x))
        atomicAdd(&deg[ovfA_list[t] & 0xFFFFu], 1);
}

// ---------------------------------------------------------------------------
// Gather with fused mean (unchanged from R5): wave per node, quarter-wave
// per bucket entry, uint2 (4 bf16 channel) loads, next-node prefetch.
// ---------------------------------------------------------------------------
__global__ void gather_kernel(const uint2* __restrict__ h64,
                              const int* __restrict__ deg,
                              const unsigned short* __restrict__ bucket,
                              float4* __restrict__ out4,
                              int n_nodes) {
    const int lane = (int)threadIdx.x & 63;
    const int q = lane >> 4;
    const int j = lane & 15;
    const int wave = (int)((blockIdx.x * blockDim.x + threadIdx.x) >> 6);
    const int nwaves = (int)((gridDim.x * blockDim.x) >> 6);

    int node = wave;
    if (node >= n_nodes) return;
    int d_nxt = deg[node];
    int my_nxt = (int)bucket[(size_t)node * CAP + lane];

    while (node < n_nodes) {
        const int d = d_nxt;
        const int mycol = my_nxt;
        const int nxt = node + nwaves;
        if (nxt < n_nodes) {
            d_nxt = deg[nxt];
            my_nxt = (int)bucket[(size_t)nxt * CAP + lane];
        }

        const int dc = d < CAP ? d : CAP;
        const int ngr = (dc + 3) >> 2;
        float a0 = 0.f, a1 = 0.f, a2 = 0.f, a3 = 0.f;
        float b0 = 0.f, b1 = 0.f, b2 = 0.f, b3 = 0.f;
        int g = 0;
        for (; g + 2 <= ngr; g += 2) {
            const int iA = __shfl(mycol, 4 * g + q);
            const int iB = __shfl(mycol, 4 * g + 4 + q);
            uint2 wA = h64[(size_t)iA * 16 + j];
            uint2 wB = h64[(size_t)iB * 16 + j];
            if (4 * g + q >= dc)     { wA.x = 0u; wA.y = 0u; }
            if (4 * g + 4 + q >= dc) { wB.x = 0u; wB.y = 0u; }
            a0 += bflo(wA.x); a1 += bfhi(wA.x); a2 += bflo(wA.y); a3 += bfhi(wA.y);
            b0 += bflo(wB.x); b1 += bfhi(wB.x); b2 += bflo(wB.y); b3 += bfhi(wB.y);
        }
        for (; g < ngr; ++g) {
            const int iA = __shfl(mycol, 4 * g + q);
            uint2 wA = h64[(size_t)iA * 16 + j];
            if (4 * g + q >= dc) { wA.x = 0u; wA.y = 0u; }
            a0 += bflo(wA.x); a1 += bfhi(wA.x); a2 += bflo(wA.y); a3 += bfhi(wA.y);
        }
        a0 += b0; a1 += b1; a2 += b2; a3 += b3;
        a0 += __shfl_xor(a0, 16); a0 += __shfl_xor(a0, 32);
        a1 += __shfl_xor(a1, 16); a1 += __shfl_xor(a1, 32);
        a2 += __shfl_xor(a2, 16); a2 += __shfl_xor(a2, 32);
        a3 += __shfl_xor(a3, 16); a3 += __shfl_xor(a3, 32);
        if (q == 0) {
            const float inv = 1.0f / fmaxf((float)d, 1.0f);
            float4 o;
            o.x = a0 * inv; o.y = a1 * inv; o.z = a2 * inv; o.w = a3 * inv;
            out4[(size_t)node * (D_OUT / 4) + j] = o;
        }
        node = nxt;
    }
}

// ---------------------------------------------------------------------------
// Overflow apply (normally zero work): both lists hold packed (r | c<<16);
// adds h[c]/deg[r] into out.
// ---------------------------------------------------------------------------
__global__ void ovf_apply_kernel(const unsigned short* __restrict__ h,
                                 const int* __restrict__ deg,
                                 const unsigned* __restrict__ listA,
                                 const int* __restrict__ cntA_p, int capA,
                                 const unsigned* __restrict__ listB,
                                 const int* __restrict__ cntB_p, int capB,
                                 float* __restrict__ out) {
    int cA = *cntA_p; if (cA > capA) cA = capA;
    int cB = *cntB_p; if (cB > capB) cB = capB;
    const long long n_tasks = (long long)(cA + cB) * D_OUT;
    long long t = (long long)blockIdx.x * blockDim.x + threadIdx.x;
    const long long stride = (long long)gridDim.x * blockDim.x;
    for (; t < n_tasks; t += stride) {
        const int k = (int)(t >> 6);
        const int lane = (int)(t & 63);
        const unsigned rec = (k < cA) ? listA[k] : listB[k - cA];
        const int r = (int)(rec & 0xFFFFu);
        const int c = (int)(rec >> 16);
        union { unsigned u; float f; } v;
        v.u = ((unsigned)h[(size_t)c * D_OUT + lane]) << 16;
        atomicAdd(&out[(size_t)r * D_OUT + lane],
                  v.f / fmaxf((float)deg[r], 1.0f));
    }
}

// ---------------------------------------------------------------------------
// Fallback path (ws too small or n_nodes > 65536): fp32 h + atomic scatter.
// ---------------------------------------------------------------------------
__global__ void proj_only_kernel(const float* __restrict__ x,
                                 const float* __restrict__ W,
                                 const float* __restrict__ bvec,
                                 float* __restrict__ h, int n_nodes) {
    const int lane = (int)threadIdx.x & 63;
    const int wave = (int)((blockIdx.x * blockDim.x + threadIdx.x) >> 6);
    const int nwaves = (int)((gridDim.x * blockDim.x) >> 6);
    const float bias = bvec[lane];
    for (int node = wave; node < n_nodes; node += nwaves) {
        const float* xr = &x[(size_t)node * D_IN];
        float acc = bias;
#pragma unroll
        for (int k = 0; k < D_IN; ++k) acc += xr[k] * W[lane * D_IN + k];
        h[(size_t)node * D_OUT + lane] = acc;
    }
}

__global__ void scatter_kernel(const float* __restrict__ h,
                               const int* __restrict__ row,
                               const int* __restrict__ col,
                               float* __restrict__ out,
                               int* __restrict__ deg,
                               long long n_tasks) {
    long long t = (long long)blockIdx.x * blockDim.x + threadIdx.x;
    const long long stride = (long long)gridDim.x * blockDim.x;
    for (; t < n_tasks; t += stride) {
        const int e = (int)(t >> 6);
        const int c = (int)(t & 63);
        atomicAdd(&out[(size_t)row[e] * D_OUT + c], h[(size_t)col[e] * D_OUT + c]);
        if (c == 0) atomicAdd(&deg[row[e]], 1);
    }
}

__global__ void div_kernel(float* __restrict__ out,
                           const int* __restrict__ deg, int n_total) {
    int t = blockIdx.x * blockDim.x + threadIdx.x;
    if (t < n_total) {
        out[t] *= 1.0f / fmaxf((float)deg[t >> 6], 1.0f);
    }
}

extern "C" void kernel_launch(void* const* d_in, const int* in_sizes, int n_in,
                              void* d_out, int out_size, void* d_ws, size_t ws_size,
                              hipStream_t stream) {
    const float* x   = (const float*)d_in[0];
    const float* W   = (const float*)d_in[1];
    const float* b   = (const float*)d_in[2];
    const int*   row = (const int*)d_in[3];
    const int*   col = (const int*)d_in[4];
    float* out = (float*)d_out;

    const int n_nodes = in_sizes[0] / D_IN;
    const int n_edges = in_sizes[3];
    const int n_bins  = (n_nodes + 255) >> BIN_SHIFT;

    // Workspace: h(bf16) | deg | [ovfA_cnt ovfB_cnt pad 256B] | cursor(padded)
    //            | ovfA_list | ovfB_list | bucket(ushort) | scratch
    char* p = (char*)d_ws;
    unsigned short* h = (unsigned short*)p;
    p += (size_t)n_nodes * D_OUT * sizeof(unsigned short);
    int* deg = (int*)p;            p += (size_t)n_nodes * sizeof(int);
    int* ovf_cnts = (int*)p;       p += 256;                       // [0]=A, [1]=B
    int* cursor = (int*)p;         p += (size_t)MAX_BINS * 16 * sizeof(int);
    unsigned* ovfA_list = (unsigned*)p;  p += (size_t)n_edges * sizeof(unsigned);
    unsigned* ovfB_list = (unsigned*)p;  p += (size_t)n_edges * sizeof(unsigned);
    unsigned short* bucket = (unsigned short*)p;
    p += (size_t)n_nodes * CAP * sizeof(unsigned short);
    unsigned* scratch = (unsigned*)p;
    p += (size_t)n_bins * BIN_CAP * sizeof(unsigned);
    const size_t needed = (size_t)(p - (char*)d_ws);

    if (ws_size >= needed && n_nodes <= MAX_USHORT_NODES) {
        // zero: ovf counters + padded cursor (contiguous)
        hipMemsetAsync(ovf_cnts, 0, 256 + (size_t)MAX_BINS * 16 * sizeof(int),
                       stream);

        // 1) projection
        const int ntiles = (n_nodes + 15) / 16;
        const int proj_blocks = (ntiles + 7) / 8;
        proj_kernel<<<proj_blocks, 256, 0, stream>>>(x, W, b, h, n_nodes);

        // 2) binned bucket build (no global returning atomics per edge)
        binpass1_kernel<<<P1_BLOCKS, P1_THREADS, 0, stream>>>(
            row, col, scratch, cursor, &ovf_cnts[0], ovfA_list, n_edges,
            n_edges, n_bins);
        binpass2_kernel<<<n_bins, P2_THREADS, 0, stream>>>(
            scratch, cursor, deg, bucket, &ovf_cnts[1], ovfB_list, n_edges,
            n_nodes);
        degfix_kernel<<<64, 256, 0, stream>>>(ovfA_list, &ovf_cnts[0], n_edges,
                                              deg);

        // 3) gather (fused mean)
        const int grid = (n_nodes + 3) / 4;
        gather_kernel<<<grid, 256, 0, stream>>>((const uint2*)h, deg, bucket,
                                                (float4*)out, n_nodes);

        // 4) overflow contributions (zero work in practice)
        ovf_apply_kernel<<<256, 256, 0, stream>>>(h, deg, ovfA_list,
                                                  &ovf_cnts[0], n_edges,
                                                  ovfB_list, &ovf_cnts[1],
                                                  n_edges, out);
    } else {
        // fallback: fp32 h + atomic scatter
        float* hf = (float*)d_ws;
        int* degf = (int*)((char*)d_ws + (size_t)n_nodes * D_OUT * sizeof(float));
        hipMemsetAsync(out, 0, (size_t)out_size * sizeof(float), stream);
        hipMemsetAsync(degf, 0, (size_t)n_nodes * sizeof(int), stream);
        proj_only_kernel<<<1024, 256, 0, stream>>>(x, W, b, hf, n_nodes);
        const long long n_tasks = (long long)n_edges * D_OUT;
        scatter_kernel<<<16384, 256, 0, stream>>>(hf, row, col, out, degf, n_tasks);
        const int n_total = n_nodes * D_OUT;
        div_kernel<<<(n_total + 255) / 256, 256, 0, stream>>>(out, degf, n_total);
    }
}